// Round 1
// baseline (10562.579 us; speedup 1.0000x reference)
//
#include <hip/hip_runtime.h>

#define NB 4096
#define ND 64
#define NH 256
#define NT 50
#define ROWS 16   // rows per block

// LDS layout (floats), padded strides to avoid bank conflicts
#define W2S 68
#define YIS 68
#define ZS  260
#define YI_OFF (NH * W2S)                 // 17408
#define Z_OFF  (YI_OFF + ROWS * YIS)      // 18496
#define LDS_FLOATS (Z_OFF + ROWS * ZS)    // 22656 -> 90624 bytes

__device__ __forceinline__ float fast_tanh(float x) {
  // tanh(x) = 1 - 2/(exp(2x)+1); safe at +-inf (exp->inf => 1, exp->0 => -1)
  float e = __expf(2.0f * x);
  return 1.0f - 2.0f * __builtin_amdgcn_rcpf(e + 1.0f);
}

#define AXPY_IP(acc, c, v)                                                     \
  do {                                                                         \
    acc.x = fmaf((c), (v).x, acc.x);                                           \
    acc.y = fmaf((c), (v).y, acc.y);                                           \
    acc.z = fmaf((c), (v).z, acc.z);                                           \
    acc.w = fmaf((c), (v).w, acc.w);                                           \
  } while (0)

extern "C" __global__ void __launch_bounds__(256, 1)
ode_kernel(const float* __restrict__ y0,
           const float* __restrict__ tt,
           const float* __restrict__ W1,
           const float* __restrict__ b1,
           const float* __restrict__ W2,
           const float* __restrict__ b2,
           float* __restrict__ out)
{
  extern __shared__ float smem[];
  float* __restrict__ sW2 = smem;          // [NH][W2S]
  float* __restrict__ sYI = smem + YI_OFF; // [ROWS][YIS]
  float* __restrict__ sZ  = smem + Z_OFF;  // [ROWS][ZS]

  const int tid = threadIdx.x;   // doubles as hidden-unit index j for GEMM1
  const int rr  = tid >> 4;      // row-in-block (0..15)
  const int cc  = tid & 15;      // dim-quad (0..15) -> dims 4*cc..4*cc+3
  const int row = (int)blockIdx.x * ROWS + rr;

  // Stage W2 into LDS (coalesced)
  for (int i = tid; i < NH * ND; i += 256) {
    sW2[(i >> 6) * W2S + (i & 63)] = W2[i];
  }

  // W1 column tid into registers (coalesced: lanes read consecutive j)
  float w1c[ND];
#pragma unroll
  for (int d = 0; d < ND; ++d) w1c[d] = W1[d * NH + tid];
  const float b1j = b1[tid];
  const float4 b2q = *(const float4*)&b2[cc * 4];

  // state slice: y[row][4cc..4cc+3]
  float4 y4 = *(const float4*)&y0[row * ND + cc * 4];
  *(float4*)&out[row * ND + cc * 4] = y4;   // out[0] = y0

  __syncthreads();  // sW2 ready

  // f(yi) = tanh(yi @ W1 + b1) @ W2 + b2, returns this thread's 4-dim slice
  auto feval = [&](float4 yiv) -> float4 {
    *(float4*)&sYI[rr * YIS + cc * 4] = yiv;
    __syncthreads();

    // GEMM1: z_j[r] for all 16 rows, j = tid, W1 column in registers
    float z[ROWS];
#pragma unroll
    for (int r = 0; r < ROWS; ++r) z[r] = b1j;
#pragma unroll
    for (int db = 0; db < 16; ++db) {
      const float wa = w1c[db * 4 + 0];
      const float wb = w1c[db * 4 + 1];
      const float wc = w1c[db * 4 + 2];
      const float wd = w1c[db * 4 + 3];
#pragma unroll
      for (int r = 0; r < ROWS; ++r) {
        const float4 a = *(const float4*)&sYI[r * YIS + db * 4];
        z[r] = fmaf(a.x, wa, z[r]);
        z[r] = fmaf(a.y, wb, z[r]);
        z[r] = fmaf(a.z, wc, z[r]);
        z[r] = fmaf(a.w, wd, z[r]);
      }
    }
#pragma unroll
    for (int r = 0; r < ROWS; ++r) sZ[r * ZS + tid] = fast_tanh(z[r]);
    __syncthreads();

    // GEMM2: out[rr][4cc..+3] = sum_j z[rr][j] * W2[j][4cc..+3] + b2
    float o0 = b2q.x, o1 = b2q.y, o2 = b2q.z, o3 = b2q.w;
    const float* __restrict__ zrow = sZ + rr * ZS;
    const float* __restrict__ wcol = sW2 + cc * 4;
#pragma unroll 4
    for (int jb = 0; jb < NH; jb += 4) {
      const float4 zv = *(const float4*)&zrow[jb];
      const float4 wA = *(const float4*)&wcol[(jb + 0) * W2S];
      const float4 wB = *(const float4*)&wcol[(jb + 1) * W2S];
      const float4 wC = *(const float4*)&wcol[(jb + 2) * W2S];
      const float4 wD = *(const float4*)&wcol[(jb + 3) * W2S];
      o0 = fmaf(zv.x, wA.x, o0); o1 = fmaf(zv.x, wA.y, o1);
      o2 = fmaf(zv.x, wA.z, o2); o3 = fmaf(zv.x, wA.w, o3);
      o0 = fmaf(zv.y, wB.x, o0); o1 = fmaf(zv.y, wB.y, o1);
      o2 = fmaf(zv.y, wB.z, o2); o3 = fmaf(zv.y, wB.w, o3);
      o0 = fmaf(zv.z, wC.x, o0); o1 = fmaf(zv.z, wC.y, o1);
      o2 = fmaf(zv.z, wC.z, o2); o3 = fmaf(zv.z, wC.w, o3);
      o0 = fmaf(zv.w, wD.x, o0); o1 = fmaf(zv.w, wD.y, o1);
      o2 = fmaf(zv.w, wD.z, o2); o3 = fmaf(zv.w, wD.w, o3);
    }
    return make_float4(o0, o1, o2, o3);
  };

  // Dormand-Prince 5(4) tableau (5th-order solution row), as float constants
  const float A10 = (float)(1.0 / 5.0);
  const float A20 = (float)(3.0 / 40.0),      A21 = (float)(9.0 / 40.0);
  const float A30 = (float)(44.0 / 45.0),     A31 = (float)(-56.0 / 15.0),
              A32 = (float)(32.0 / 9.0);
  const float A40 = (float)(19372.0 / 6561.0), A41 = (float)(-25360.0 / 2187.0),
              A42 = (float)(64448.0 / 6561.0), A43 = (float)(-212.0 / 729.0);
  const float A50 = (float)(9017.0 / 3168.0),  A51 = (float)(-355.0 / 33.0),
              A52 = (float)(46732.0 / 5247.0), A53 = (float)(49.0 / 176.0),
              A54 = (float)(-5103.0 / 18656.0);
  const float B0 = (float)(35.0 / 384.0),      B2 = (float)(500.0 / 1113.0),
              B3 = (float)(125.0 / 192.0),     B4 = (float)(-2187.0 / 6784.0),
              B5 = (float)(11.0 / 84.0);

  for (int ti = 0; ti < NT - 1; ++ti) {
    const float dt = (tt[ti + 1] - tt[ti]) * 0.25f;  // /SUBSTEPS, exact pow2
    for (int ss = 0; ss < 4; ++ss) {
      float4 yi;
      const float4 k0 = feval(y4);

      yi = y4; AXPY_IP(yi, dt * A10, k0);
      const float4 k1 = feval(yi);

      yi = y4; AXPY_IP(yi, dt * A20, k0); AXPY_IP(yi, dt * A21, k1);
      const float4 k2 = feval(yi);

      yi = y4; AXPY_IP(yi, dt * A30, k0); AXPY_IP(yi, dt * A31, k1);
      AXPY_IP(yi, dt * A32, k2);
      const float4 k3 = feval(yi);

      yi = y4; AXPY_IP(yi, dt * A40, k0); AXPY_IP(yi, dt * A41, k1);
      AXPY_IP(yi, dt * A42, k2); AXPY_IP(yi, dt * A43, k3);
      const float4 k4 = feval(yi);

      yi = y4; AXPY_IP(yi, dt * A50, k0); AXPY_IP(yi, dt * A51, k1);
      AXPY_IP(yi, dt * A52, k2); AXPY_IP(yi, dt * A53, k3);
      AXPY_IP(yi, dt * A54, k4);
      const float4 k5 = feval(yi);

      // y_new = y + dt*(B0*k0 + B2*k2 + B3*k3 + B4*k4 + B5*k5)   (B1 = 0)
      AXPY_IP(y4, dt * B0, k0);
      AXPY_IP(y4, dt * B2, k2);
      AXPY_IP(y4, dt * B3, k3);
      AXPY_IP(y4, dt * B4, k4);
      AXPY_IP(y4, dt * B5, k5);
    }
    *(float4*)&out[(size_t)(ti + 1) * NB * ND + row * ND + cc * 4] = y4;
  }
}

extern "C" void kernel_launch(void* const* d_in, const int* in_sizes, int n_in,
                              void* d_out, int out_size, void* d_ws, size_t ws_size,
                              hipStream_t stream) {
  const float* y0 = (const float*)d_in[0];
  const float* tt = (const float*)d_in[1];
  const float* W1 = (const float*)d_in[2];
  const float* b1 = (const float*)d_in[3];
  const float* W2 = (const float*)d_in[4];
  const float* b2 = (const float*)d_in[5];
  float* out = (float*)d_out;

  const size_t lds_bytes = (size_t)LDS_FLOATS * sizeof(float);  // 90624 B
  hipFuncSetAttribute((const void*)ode_kernel,
                      hipFuncAttributeMaxDynamicSharedMemorySize,
                      (int)lds_bytes);
  hipLaunchKernelGGL(ode_kernel, dim3(NB / ROWS), dim3(256), lds_bytes, stream,
                     y0, tt, W1, b1, W2, b2, out);
}